// Round 1
// baseline (376.067 us; speedup 1.0000x reference)
//
#include <hip/hip_runtime.h>

typedef __attribute__((ext_vector_type(8))) short short8;
typedef __attribute__((ext_vector_type(4))) float f32x4;
typedef unsigned int u32;
typedef unsigned short u16;

#define DEV __device__ __forceinline__

DEV void async16(const void* g, void* l) {
  __builtin_amdgcn_global_load_lds((const __attribute__((address_space(1))) u32*)g,
                                   (__attribute__((address_space(3))) u32*)l, 16, 0, 0);
}

DEV u16 f2bf(float f) {
  u32 u = __builtin_bit_cast(u32, f);
  u32 r = (u + 0x7FFFu + ((u >> 16) & 1u)) >> 16;
  return (u16)r;
}
DEV float bf2f(u16 h) { return __builtin_bit_cast(float, (u32)h << 16); }

// ---------------- cast f32 -> bf16 ----------------
__global__ void cast_bf16_kernel(const float* __restrict__ in, u16* __restrict__ out, int n4) {
  int stride = gridDim.x * blockDim.x;
  for (int i = blockIdx.x * blockDim.x + threadIdx.x; i < n4; i += stride) {
    float4 v = reinterpret_cast<const float4*>(in)[i];
    ushort4 o = make_ushort4(f2bf(v.x), f2bf(v.y), f2bf(v.z), f2bf(v.w));
    reinterpret_cast<ushort4*>(out)[i] = o;
  }
}

// ---------------- GEMM: C[M=4096][N=2048] = A[M][K=2048] * B[N][K]^T (bf16, f32 acc)
// MODE 0: write bf16 to [B,H,S,HD] ; MODE 2: write bf16 to [B,H,HD,S] ; MODE 3: write f32 row-major
template <int MODE>
__global__ __launch_bounds__(256) void gemm_bt(const u16* __restrict__ A,
                                               const u16* __restrict__ Bw,
                                               void* __restrict__ C) {
  constexpr int K = 2048;
  __shared__ char sm[32768];  // A tile [128][64] @0, B tile [128][64] @16384, swizzled
  const int tid = threadIdx.x;
  const int lane = tid & 63;
  const int w = tid >> 6;
  const int bx = blockIdx.x & 15;   // N/128 = 16
  const int by = blockIdx.x >> 4;   // M/128 = 32
  const int row0 = by * 128, col0 = bx * 128;
  const int wr = (w >> 1) * 64, wc = (w & 1) * 64;
  f32x4 acc[4][4] = {};

  for (int k0 = 0; k0 < K; k0 += 64) {
    __syncthreads();
#pragma unroll
    for (int i = 0; i < 4; ++i) {
      int slot = tid + i * 256;
      int r = slot >> 3, s = slot & 7;
      int sl = s ^ (r & 7);
      async16(A + (size_t)(row0 + r) * K + (k0 + sl * 8), sm + slot * 16);
    }
#pragma unroll
    for (int i = 0; i < 4; ++i) {
      int slot = tid + i * 256;
      int r = slot >> 3, s = slot & 7;
      int sl = s ^ (r & 7);
      async16(Bw + (size_t)(col0 + r) * K + (k0 + sl * 8), sm + 16384 + slot * 16);
    }
    __syncthreads();
#pragma unroll
    for (int kk = 0; kk < 2; ++kk) {
      short8 af[4], bfr[4];
#pragma unroll
      for (int mi = 0; mi < 4; ++mi) {
        int r = wr + mi * 16 + (lane & 15);
        int ps = (kk * 4 + (lane >> 4)) ^ (r & 7);
        af[mi] = *reinterpret_cast<const short8*>(sm + r * 128 + ps * 16);
      }
#pragma unroll
      for (int ni = 0; ni < 4; ++ni) {
        int r = wc + ni * 16 + (lane & 15);
        int ps = (kk * 4 + (lane >> 4)) ^ (r & 7);
        bfr[ni] = *reinterpret_cast<const short8*>(sm + 16384 + r * 128 + ps * 16);
      }
#pragma unroll
      for (int mi = 0; mi < 4; ++mi)
#pragma unroll
        for (int ni = 0; ni < 4; ++ni)
          acc[mi][ni] = __builtin_amdgcn_mfma_f32_16x16x32_bf16(af[mi], bfr[ni], acc[mi][ni], 0, 0, 0);
    }
  }
  // epilogue
#pragma unroll
  for (int mi = 0; mi < 4; ++mi)
#pragma unroll
    for (int ni = 0; ni < 4; ++ni)
#pragma unroll
      for (int r = 0; r < 4; ++r) {
        int gm = row0 + wr + mi * 16 + ((lane >> 4) << 2) + r;
        int gn = col0 + wc + ni * 16 + (lane & 15);
        float v = acc[mi][ni][r];
        if constexpr (MODE == 0) {
          int b = gm >> 11, s = gm & 2047, h = gn >> 7, hd = gn & 127;
          ((u16*)C)[(size_t)((b << 4) | h) * 262144 + (s << 7) + hd] = f2bf(v);
        } else if constexpr (MODE == 2) {
          int b = gm >> 11, s = gm & 2047, h = gn >> 7, hd = gn & 127;
          ((u16*)C)[(size_t)((b << 4) | h) * 262144 + (hd << 11) + s] = f2bf(v);
        } else {
          ((float*)C)[((size_t)gm << 11) + gn] = v;
        }
      }
}

// ---------------- RoPE in-place on q_ws/k_ws [B,H,S,HD]; q additionally scaled by 1/sqrt(HD)
__global__ void rope_kernel(u16* __restrict__ q, u16* __restrict__ k,
                            const float* __restrict__ cb, const float* __restrict__ sb) {
  const float rs = 0.08838834764831845f;  // 1/sqrt(128)
  const int NP = 2 * 16 * 2048 * 64;      // pairs per tensor
  int stride = gridDim.x * blockDim.x;
  for (int i = blockIdx.x * blockDim.x + threadIdx.x; i < 2 * NP; i += stride) {
    int p = (i < NP) ? i : i - NP;
    u16* base = (i < NP) ? q : k;
    float sc = (i < NP) ? rs : 1.0f;
    int fi = p & 63;
    int s = (p >> 6) & 2047;
    u32 v = *reinterpret_cast<u32*>(base + 2 * (size_t)p);
    float xr = bf2f((u16)(v & 0xFFFFu)), xi = bf2f((u16)(v >> 16));
    float c = cb[(s << 6) + fi], sn = sb[(s << 6) + fi];
    float orr = (xr * c - xi * sn) * sc;
    float oi = (xr * sn + xi * c) * sc;
    *reinterpret_cast<u32*>(base + 2 * (size_t)p) = (u32)f2bf(orr) | ((u32)f2bf(oi) << 16);
  }
}

// ---------------- causal flash attention ----------------
// grid: (B*H) * (S/64) blocks, 256 threads (4 waves x 16 q-rows)
__global__ __launch_bounds__(256) void attn_kernel(const u16* __restrict__ q_ws,
                                                   const u16* __restrict__ k_ws,
                                                   const u16* __restrict__ vt_ws,
                                                   u16* __restrict__ attn_ws) {
  constexpr int S = 2048, HD = 128;
  __shared__ char sm[16384 * 2 + 8192];  // K tile [64][128]@0, Vt tile [128][64]@16384, P @32768 (per-wave 2KB)
  const int tid = threadIdx.x, lane = tid & 63, w = tid >> 6;
  const int qb = blockIdx.x & 31;
  const int bh = blockIdx.x >> 5;  // 0..31
  const int q0 = qb * 64;
  const u16* qp = q_ws + (size_t)bh * S * HD;
  const u16* kp = k_ws + (size_t)bh * S * HD;
  const u16* vp = vt_ws + (size_t)bh * HD * S;

  short8 qf[4];
  {
    int qrow = q0 + w * 16 + (lane & 15);
    const u16* qr = qp + (size_t)qrow * HD + ((lane >> 4) << 3);
#pragma unroll
    for (int d = 0; d < 4; ++d) qf[d] = *reinterpret_cast<const short8*>(qr + d * 32);
  }
  f32x4 accO[8] = {};
  float mrow[4] = {-1e30f, -1e30f, -1e30f, -1e30f};
  float lrow[4] = {0.f, 0.f, 0.f, 0.f};

  const int kv_end = q0 + 64;
  for (int kv0 = 0; kv0 < kv_end; kv0 += 64) {
    __syncthreads();
#pragma unroll
    for (int i = 0; i < 4; ++i) {  // K tile: 64 rows x 16 slots
      int slot = tid + i * 256;
      int r = slot >> 4, s = slot & 15;
      int ls = (s & 8) | ((s ^ (r & 7)) & 7);
      async16(kp + (size_t)(kv0 + r) * HD + ls * 8, sm + slot * 16);
    }
#pragma unroll
    for (int i = 0; i < 4; ++i) {  // Vt tile: 128 rows x 8 slots
      int slot = tid + i * 256;
      int r = slot >> 3, s = slot & 7;
      int ls = s ^ (r & 7);
      async16(vp + (size_t)r * S + (kv0 + ls * 8), sm + 16384 + slot * 16);
    }
    __syncthreads();

    f32x4 sacc[4] = {};
#pragma unroll
    for (int jc = 0; jc < 4; ++jc) {
#pragma unroll
      for (int dc = 0; dc < 4; ++dc) {
        int r = jc * 16 + (lane & 15);
        int ls = dc * 4 + (lane >> 4);
        int ps = (ls & 8) | ((ls ^ (r & 7)) & 7);
        short8 kf = *reinterpret_cast<const short8*>(sm + r * 256 + ps * 16);
        sacc[jc] = __builtin_amdgcn_mfma_f32_16x16x32_bf16(qf[dc], kf, sacc[jc], 0, 0, 0);
      }
    }
    if (kv0 + 63 > q0 + w * 16) {  // causal mask needed in this tile
#pragma unroll
      for (int jc = 0; jc < 4; ++jc)
#pragma unroll
        for (int r = 0; r < 4; ++r) {
          int j = kv0 + jc * 16 + (lane & 15);
          int iq = q0 + w * 16 + ((lane >> 4) << 2) + r;
          if (j > iq) sacc[jc][r] = -__builtin_inff();
        }
    }
    // online softmax (rows live across the 16-lane group)
    float scl[4], psum[4];
#pragma unroll
    for (int r = 0; r < 4; ++r) {
      float v = fmaxf(fmaxf(sacc[0][r], sacc[1][r]), fmaxf(sacc[2][r], sacc[3][r]));
#pragma unroll
      for (int off = 1; off < 16; off <<= 1) v = fmaxf(v, __shfl_xor(v, off, 64));
      float mn = fmaxf(mrow[r], v);
      scl[r] = __expf(mrow[r] - mn);
      mrow[r] = mn;
      psum[r] = 0.f;
    }
#pragma unroll
    for (int jc = 0; jc < 4; ++jc)
#pragma unroll
      for (int r = 0; r < 4; ++r) {
        float pv = __expf(sacc[jc][r] - mrow[r]);
        sacc[jc][r] = pv;
        psum[r] += pv;
      }
#pragma unroll
    for (int r = 0; r < 4; ++r) {
#pragma unroll
      for (int off = 1; off < 16; off <<= 1) psum[r] += __shfl_xor(psum[r], off, 64);
      lrow[r] = lrow[r] * scl[r] + psum[r];
    }
#pragma unroll
    for (int n = 0; n < 8; ++n)
#pragma unroll
      for (int r = 0; r < 4; ++r) accO[n][r] *= scl[r];

    // P (C-layout) -> per-wave swizzled LDS -> A-fragment layout
    char* pbase = sm + 32768 + w * 2048;
    asm volatile("s_waitcnt lgkmcnt(0)" ::: "memory");
#pragma unroll
    for (int jc = 0; jc < 4; ++jc)
#pragma unroll
      for (int r = 0; r < 4; ++r) {
        int row = ((lane >> 4) << 2) + r;
        int col = jc * 16 + (lane & 15);
        *reinterpret_cast<u16*>(pbase + row * 128 + (((col >> 3) ^ (row & 7)) << 4) +
                                ((col & 7) << 1)) = f2bf(sacc[jc][r]);
      }
    asm volatile("s_waitcnt lgkmcnt(0)" ::: "memory");
#pragma unroll
    for (int jch = 0; jch < 2; ++jch) {
      int prow = lane & 15;
      int pls = (jch * 4 + (lane >> 4)) ^ (prow & 7);
      short8 pf = *reinterpret_cast<const short8*>(pbase + prow * 128 + pls * 16);
#pragma unroll
      for (int n = 0; n < 8; ++n) {
        int vr = n * 16 + (lane & 15);
        int vls = (jch * 4 + (lane >> 4)) ^ (vr & 7);
        short8 vf = *reinterpret_cast<const short8*>(sm + 16384 + vr * 128 + vls * 16);
        accO[n] = __builtin_amdgcn_mfma_f32_16x16x32_bf16(pf, vf, accO[n], 0, 0, 0);
      }
    }
  }
  // epilogue: O /= l, write bf16 to attn_ws [B,S,D]
  const int b = bh >> 4, h = bh & 15;
#pragma unroll
  for (int r = 0; r < 4; ++r) {
    float inv = 1.0f / lrow[r];
    int qrow = q0 + w * 16 + ((lane >> 4) << 2) + r;
    size_t rowbase = ((size_t)(b * 2048 + qrow) << 11) + (h << 7);
#pragma unroll
    for (int n = 0; n < 8; ++n)
      attn_ws[rowbase + n * 16 + (lane & 15)] = f2bf(accO[n][r] * inv);
  }
}

extern "C" void kernel_launch(void* const* d_in, const int* in_sizes, int n_in,
                              void* d_out, int out_size, void* d_ws, size_t ws_size,
                              hipStream_t stream) {
  const float* x = (const float*)d_in[0];
  // d_in[1] = start_pos (0), d_in[4] = mask (causal) — handled analytically
  const float* cb = (const float*)d_in[2];
  const float* sb = (const float*)d_in[3];
  const float* wq = (const float*)d_in[5];
  const float* wk = (const float*)d_in[6];
  const float* wv = (const float*)d_in[7];
  const float* wo = (const float*)d_in[8];

  char* p = (char*)d_ws;
  u16* xb  = (u16*)p; p += (size_t)4096 * 2048 * 2;
  u16* wqb = (u16*)p; p += (size_t)2048 * 2048 * 2;
  u16* wkb = (u16*)p; p += (size_t)2048 * 2048 * 2;
  u16* wvb = (u16*)p; p += (size_t)2048 * 2048 * 2;
  u16* wob = (u16*)p; p += (size_t)2048 * 2048 * 2;
  u16* q_ws = (u16*)p; p += (size_t)4096 * 2048 * 2;
  u16* k_ws = (u16*)p; p += (size_t)4096 * 2048 * 2;
  u16* vt_ws = (u16*)p; p += (size_t)4096 * 2048 * 2;
  u16* attn_ws = xb;  // xb is dead after the V projection; reuse it

  cast_bf16_kernel<<<2048, 256, 0, stream>>>(x, xb, 4096 * 2048 / 4);
  cast_bf16_kernel<<<1024, 256, 0, stream>>>(wq, wqb, 2048 * 2048 / 4);
  cast_bf16_kernel<<<1024, 256, 0, stream>>>(wk, wkb, 2048 * 2048 / 4);
  cast_bf16_kernel<<<1024, 256, 0, stream>>>(wv, wvb, 2048 * 2048 / 4);
  cast_bf16_kernel<<<1024, 256, 0, stream>>>(wo, wob, 2048 * 2048 / 4);

  gemm_bt<0><<<512, 256, 0, stream>>>(xb, wqb, q_ws);
  gemm_bt<0><<<512, 256, 0, stream>>>(xb, wkb, k_ws);
  gemm_bt<2><<<512, 256, 0, stream>>>(xb, wvb, vt_ws);

  rope_kernel<<<2048, 256, 0, stream>>>(q_ws, k_ws, cb, sb);

  attn_kernel<<<1024, 256, 0, stream>>>(q_ws, k_ws, vt_ws, attn_ws);

  gemm_bt<3><<<512, 256, 0, stream>>>(attn_ws, wob, d_out);
}

// Round 2
// 349.874 us; speedup vs baseline: 1.0749x; 1.0749x over previous
//
#include <hip/hip_runtime.h>

typedef __attribute__((ext_vector_type(8))) short short8;
typedef __attribute__((ext_vector_type(4))) float f32x4;
typedef unsigned int u32;
typedef unsigned short u16;

#define DEV __device__ __forceinline__

DEV void async16(const void* g, void* l) {
  __builtin_amdgcn_global_load_lds((const __attribute__((address_space(1))) u32*)g,
                                   (__attribute__((address_space(3))) u32*)l, 16, 0, 0);
}

DEV u16 f2bf(float f) {
  u32 u = __builtin_bit_cast(u32, f);
  u32 r = (u + 0x7FFFu + ((u >> 16) & 1u)) >> 16;
  return (u16)r;
}
DEV float bf2f(u16 h) { return __builtin_bit_cast(float, (u32)h << 16); }

// ---------------- cast f32 -> bf16 ----------------
__global__ void cast_bf16_kernel(const float* __restrict__ in, u16* __restrict__ out, int n4) {
  int stride = gridDim.x * blockDim.x;
  for (int i = blockIdx.x * blockDim.x + threadIdx.x; i < n4; i += stride) {
    float4 v = reinterpret_cast<const float4*>(in)[i];
    ushort4 o = make_ushort4(f2bf(v.x), f2bf(v.y), f2bf(v.z), f2bf(v.w));
    reinterpret_cast<ushort4*>(out)[i] = o;
  }
}

// ---------------- GEMM: C[M=4096][N=2048] = A[M][K=2048] * B[N][K]^T (bf16, f32 acc)
// MODE 0: write bf16 to [B,H,S,HD] ; MODE 2: write bf16 to [B,H,HD,S] ; MODE 3: write f32 row-major
template <int MODE>
__global__ __launch_bounds__(256) void gemm_bt(const u16* __restrict__ A,
                                               const u16* __restrict__ Bw,
                                               void* __restrict__ C) {
  constexpr int K = 2048;
  __shared__ char sm[32768];  // A tile [128][64] @0, B tile [128][64] @16384, swizzled
  const int tid = threadIdx.x;
  const int lane = tid & 63;
  const int w = tid >> 6;
  const int bx = blockIdx.x & 15;   // N/128 = 16
  const int by = blockIdx.x >> 4;   // M/128 = 32
  const int row0 = by * 128, col0 = bx * 128;
  const int wr = (w >> 1) * 64, wc = (w & 1) * 64;
  f32x4 acc[4][4] = {};

  for (int k0 = 0; k0 < K; k0 += 64) {
    __syncthreads();
#pragma unroll
    for (int i = 0; i < 4; ++i) {
      int slot = tid + i * 256;
      int r = slot >> 3, s = slot & 7;
      int sl = s ^ (r & 7);
      async16(A + (size_t)(row0 + r) * K + (k0 + sl * 8), sm + slot * 16);
    }
#pragma unroll
    for (int i = 0; i < 4; ++i) {
      int slot = tid + i * 256;
      int r = slot >> 3, s = slot & 7;
      int sl = s ^ (r & 7);
      async16(Bw + (size_t)(col0 + r) * K + (k0 + sl * 8), sm + 16384 + slot * 16);
    }
    __syncthreads();
#pragma unroll
    for (int kk = 0; kk < 2; ++kk) {
      short8 af[4], bfr[4];
#pragma unroll
      for (int mi = 0; mi < 4; ++mi) {
        int r = wr + mi * 16 + (lane & 15);
        int ps = (kk * 4 + (lane >> 4)) ^ (r & 7);
        af[mi] = *reinterpret_cast<const short8*>(sm + r * 128 + ps * 16);
      }
#pragma unroll
      for (int ni = 0; ni < 4; ++ni) {
        int r = wc + ni * 16 + (lane & 15);
        int ps = (kk * 4 + (lane >> 4)) ^ (r & 7);
        bfr[ni] = *reinterpret_cast<const short8*>(sm + 16384 + r * 128 + ps * 16);
      }
#pragma unroll
      for (int mi = 0; mi < 4; ++mi)
#pragma unroll
        for (int ni = 0; ni < 4; ++ni)
          acc[mi][ni] = __builtin_amdgcn_mfma_f32_16x16x32_bf16(af[mi], bfr[ni], acc[mi][ni], 0, 0, 0);
    }
  }
  // epilogue
#pragma unroll
  for (int mi = 0; mi < 4; ++mi)
#pragma unroll
    for (int ni = 0; ni < 4; ++ni)
#pragma unroll
      for (int r = 0; r < 4; ++r) {
        int gm = row0 + wr + mi * 16 + ((lane >> 4) << 2) + r;
        int gn = col0 + wc + ni * 16 + (lane & 15);
        float v = acc[mi][ni][r];
        if constexpr (MODE == 0) {
          int b = gm >> 11, s = gm & 2047, h = gn >> 7, hd = gn & 127;
          ((u16*)C)[(size_t)((b << 4) | h) * 262144 + (s << 7) + hd] = f2bf(v);
        } else if constexpr (MODE == 2) {
          int b = gm >> 11, s = gm & 2047, h = gn >> 7, hd = gn & 127;
          ((u16*)C)[(size_t)((b << 4) | h) * 262144 + (hd << 11) + s] = f2bf(v);
        } else {
          ((float*)C)[((size_t)gm << 11) + gn] = v;
        }
      }
}

// ---------------- RoPE in-place on q_ws/k_ws [B,H,S,HD]
// q additionally scaled by log2(e)/sqrt(HD) so attn can use exp2
__global__ void rope_kernel(u16* __restrict__ q, u16* __restrict__ k,
                            const float* __restrict__ cb, const float* __restrict__ sb) {
  const float rs = 0.127517436f;  // log2(e)/sqrt(128)
  const int NP = 2 * 16 * 2048 * 64;  // pairs per tensor
  int stride = gridDim.x * blockDim.x;
  for (int i = blockIdx.x * blockDim.x + threadIdx.x; i < 2 * NP; i += stride) {
    int p = (i < NP) ? i : i - NP;
    u16* base = (i < NP) ? q : k;
    float sc = (i < NP) ? rs : 1.0f;
    int fi = p & 63;
    int s = (p >> 6) & 2047;
    u32 v = *reinterpret_cast<u32*>(base + 2 * (size_t)p);
    float xr = bf2f((u16)(v & 0xFFFFu)), xi = bf2f((u16)(v >> 16));
    float c = cb[(s << 6) + fi], sn = sb[(s << 6) + fi];
    float orr = (xr * c - xi * sn) * sc;
    float oi = (xr * sn + xi * c) * sc;
    *reinterpret_cast<u32*>(base + 2 * (size_t)p) = (u32)f2bf(orr) | ((u32)f2bf(oi) << 16);
  }
}

// ---------------- causal flash attention ----------------
// 512 blocks = 32 bh x 16 pairs. Block processes q-tiles (pairA, 31-pairA):
// waves 0-1 own 32 rows each of tile pairA; waves 2-3 own tile 31-pairA.
// KV staged (double-buffered) over the union range; idle waves skip compute.
// Per-block work = 66 wave-tiles for every block (deterministic balance).
__global__ __launch_bounds__(256, 2) void attn_kernel(const u16* __restrict__ q_ws,
                                                      const u16* __restrict__ k_ws,
                                                      const u16* __restrict__ vt_ws,
                                                      u16* __restrict__ attn_ws) {
  constexpr int S = 2048, HD = 128;
  // dbuf b @ b*32768: K[64][128]sw (16KB) + Vt[128][64]sw (16KB). P @65536 + w*4096 (16KB)
  __shared__ char sm[81920];
  const int tid = threadIdx.x, lane = tid & 63, w = tid >> 6;
  const int pairA = blockIdx.x & 15;
  const int bh = blockIdx.x >> 4;  // 0..31
  const int qt = (w < 2) ? pairA : 31 - pairA;
  const int qr0 = qt * 64 + (w & 1) * 32;       // wave's first q row
  const int ntile_blk = 32 - pairA;             // staged kv tiles (union range)
  const int my_nt = qt + 1;                     // wave-active kv tiles

  const u16* qp = q_ws + (size_t)bh * S * HD;
  const u16* kp = k_ws + (size_t)bh * S * HD;
  const u16* vp = vt_ws + (size_t)bh * HD * S;

  short8 qf[2][4];
#pragma unroll
  for (int rb = 0; rb < 2; ++rb) {
    int qrow = qr0 + rb * 16 + (lane & 15);
    const u16* qr = qp + (size_t)qrow * HD + ((lane >> 4) << 3);
#pragma unroll
    for (int d = 0; d < 4; ++d) qf[rb][d] = *reinterpret_cast<const short8*>(qr + d * 32);
  }
  f32x4 accO[2][8] = {};
  float mrow[2][4], lrow[2][4];
#pragma unroll
  for (int rb = 0; rb < 2; ++rb)
#pragma unroll
    for (int r = 0; r < 4; ++r) { mrow[rb][r] = -1e30f; lrow[rb][r] = 0.f; }

  auto stage = [&](int bufoff, int kv0) {
#pragma unroll
    for (int i = 0; i < 4; ++i) {  // K tile: 64 rows x 16 slots
      int slot = tid + i * 256;
      int r = slot >> 4, s = slot & 15;
      int ls = (s & 8) | ((s ^ (r & 7)) & 7);
      async16(kp + (size_t)(kv0 + r) * HD + ls * 8, sm + bufoff + slot * 16);
    }
#pragma unroll
    for (int i = 0; i < 4; ++i) {  // Vt tile: 128 rows x 8 slots
      int slot = tid + i * 256;
      int r = slot >> 3, s = slot & 7;
      int ls = s ^ (r & 7);
      async16(vp + (size_t)r * S + (kv0 + ls * 8), sm + bufoff + 16384 + slot * 16);
    }
  };

  stage(0, 0);
  __syncthreads();  // drains vmcnt

  for (int t = 0; t < ntile_blk; ++t) {
    const char* kb = sm + (t & 1) * 32768;
    const char* vb = kb + 16384;
    if (t + 1 < ntile_blk) stage(((t + 1) & 1) * 32768, (t + 1) * 64);

    if (t < my_nt) {
      // ---- QK^T: each K fragment feeds both row-blocks ----
      f32x4 sacc[2][4] = {};
#pragma unroll
      for (int jc = 0; jc < 4; ++jc) {
        int r = jc * 16 + (lane & 15);
#pragma unroll
        for (int dc = 0; dc < 4; ++dc) {
          int ls = dc * 4 + (lane >> 4);
          int ps = (ls & 8) | ((ls ^ (r & 7)) & 7);
          short8 kf = *reinterpret_cast<const short8*>(kb + r * 256 + ps * 16);
          sacc[0][jc] = __builtin_amdgcn_mfma_f32_16x16x32_bf16(qf[0][dc], kf, sacc[0][jc], 0, 0, 0);
          sacc[1][jc] = __builtin_amdgcn_mfma_f32_16x16x32_bf16(qf[1][dc], kf, sacc[1][jc], 0, 0, 0);
        }
      }
      if (t * 64 + 63 > qr0) {  // causal mask may clip this tile
#pragma unroll
        for (int rb = 0; rb < 2; ++rb)
#pragma unroll
          for (int jc = 0; jc < 4; ++jc)
#pragma unroll
            for (int r = 0; r < 4; ++r) {
              int j = t * 64 + jc * 16 + (lane & 15);
              int iq = qr0 + rb * 16 + ((lane >> 4) << 2) + r;
              if (j > iq) sacc[rb][jc][r] = -__builtin_inff();
            }
      }
      // ---- online softmax (log2 domain; scores pre-scaled by log2e) ----
      float scl[2][4];
#pragma unroll
      for (int rb = 0; rb < 2; ++rb) {
        float psum[4];
#pragma unroll
        for (int r = 0; r < 4; ++r) {
          float v = fmaxf(fmaxf(sacc[rb][0][r], sacc[rb][1][r]),
                          fmaxf(sacc[rb][2][r], sacc[rb][3][r]));
#pragma unroll
          for (int off = 1; off < 16; off <<= 1) v = fmaxf(v, __shfl_xor(v, off, 64));
          float mn = fmaxf(mrow[rb][r], v);
          scl[rb][r] = exp2f(mrow[rb][r] - mn);
          mrow[rb][r] = mn;
          psum[r] = 0.f;
        }
#pragma unroll
        for (int jc = 0; jc < 4; ++jc)
#pragma unroll
          for (int r = 0; r < 4; ++r) {
            float pv = exp2f(sacc[rb][jc][r] - mrow[rb][r]);
            sacc[rb][jc][r] = pv;
            psum[r] += pv;
          }
#pragma unroll
        for (int r = 0; r < 4; ++r) {
#pragma unroll
          for (int off = 1; off < 16; off <<= 1) psum[r] += __shfl_xor(psum[r], off, 64);
          lrow[rb][r] = lrow[rb][r] * scl[rb][r] + psum[r];
        }
#pragma unroll
        for (int n = 0; n < 8; ++n)
#pragma unroll
          for (int r = 0; r < 4; ++r) accO[rb][n][r] *= scl[rb][r];
      }
      // ---- P (C-layout) -> per-wave swizzled LDS -> A-fragment layout ----
      char* pb = sm + 65536 + w * 4096;
      asm volatile("s_waitcnt lgkmcnt(0)" ::: "memory");
#pragma unroll
      for (int rb = 0; rb < 2; ++rb)
#pragma unroll
        for (int jc = 0; jc < 4; ++jc)
#pragma unroll
          for (int r = 0; r < 4; ++r) {
            int row = rb * 16 + ((lane >> 4) << 2) + r;
            int col = jc * 16 + (lane & 15);
            *reinterpret_cast<u16*>(pb + row * 128 + (((col >> 3) ^ (row & 7)) << 4) +
                                    ((col & 7) << 1)) = f2bf(sacc[rb][jc][r]);
          }
      asm volatile("s_waitcnt lgkmcnt(0)" ::: "memory");
      // ---- PV: each V fragment feeds both row-blocks ----
#pragma unroll
      for (int jch = 0; jch < 2; ++jch) {
        short8 pf[2];
#pragma unroll
        for (int rb = 0; rb < 2; ++rb) {
          int prow = rb * 16 + (lane & 15);
          int ps = (jch * 4 + (lane >> 4)) ^ (prow & 7);
          pf[rb] = *reinterpret_cast<const short8*>(pb + prow * 128 + ps * 16);
        }
#pragma unroll
        for (int n = 0; n < 8; ++n) {
          int vr = n * 16 + (lane & 15);
          int vs = (jch * 4 + (lane >> 4)) ^ (vr & 7);
          short8 vf = *reinterpret_cast<const short8*>(vb + vr * 128 + vs * 16);
          accO[0][n] = __builtin_amdgcn_mfma_f32_16x16x32_bf16(pf[0], vf, accO[0][n], 0, 0, 0);
          accO[1][n] = __builtin_amdgcn_mfma_f32_16x16x32_bf16(pf[1], vf, accO[1][n], 0, 0, 0);
        }
      }
    }
    __syncthreads();  // drains vmcnt (prefetch done) + protects dbuf reuse
  }

  // epilogue: O /= l, write bf16 to attn_ws [B,S,D]
  const int b = bh >> 4, h = bh & 15;
#pragma unroll
  for (int rb = 0; rb < 2; ++rb)
#pragma unroll
    for (int r = 0; r < 4; ++r) {
      float inv = 1.0f / lrow[rb][r];
      int qrow = qr0 + rb * 16 + ((lane >> 4) << 2) + r;
      size_t rowbase = ((size_t)(b * 2048 + qrow) << 11) + (h << 7);
#pragma unroll
      for (int n = 0; n < 8; ++n)
        attn_ws[rowbase + n * 16 + (lane & 15)] = f2bf(accO[rb][n][r] * inv);
    }
}

extern "C" void kernel_launch(void* const* d_in, const int* in_sizes, int n_in,
                              void* d_out, int out_size, void* d_ws, size_t ws_size,
                              hipStream_t stream) {
  const float* x = (const float*)d_in[0];
  // d_in[1] = start_pos (0), d_in[4] = mask (causal) — handled analytically
  const float* cb = (const float*)d_in[2];
  const float* sb = (const float*)d_in[3];
  const float* wq = (const float*)d_in[5];
  const float* wk = (const float*)d_in[6];
  const float* wv = (const float*)d_in[7];
  const float* wo = (const float*)d_in[8];

  char* p = (char*)d_ws;
  u16* xb  = (u16*)p; p += (size_t)4096 * 2048 * 2;
  u16* wqb = (u16*)p; p += (size_t)2048 * 2048 * 2;
  u16* wkb = (u16*)p; p += (size_t)2048 * 2048 * 2;
  u16* wvb = (u16*)p; p += (size_t)2048 * 2048 * 2;
  u16* wob = (u16*)p; p += (size_t)2048 * 2048 * 2;
  u16* q_ws = (u16*)p; p += (size_t)4096 * 2048 * 2;
  u16* k_ws = (u16*)p; p += (size_t)4096 * 2048 * 2;
  u16* vt_ws = (u16*)p; p += (size_t)4096 * 2048 * 2;
  u16* attn_ws = xb;  // xb is dead after the V projection; reuse it

  cast_bf16_kernel<<<2048, 256, 0, stream>>>(x, xb, 4096 * 2048 / 4);
  cast_bf16_kernel<<<1024, 256, 0, stream>>>(wq, wqb, 2048 * 2048 / 4);
  cast_bf16_kernel<<<1024, 256, 0, stream>>>(wk, wkb, 2048 * 2048 / 4);
  cast_bf16_kernel<<<1024, 256, 0, stream>>>(wv, wvb, 2048 * 2048 / 4);
  cast_bf16_kernel<<<1024, 256, 0, stream>>>(wo, wob, 2048 * 2048 / 4);

  gemm_bt<0><<<512, 256, 0, stream>>>(xb, wqb, q_ws);
  gemm_bt<0><<<512, 256, 0, stream>>>(xb, wkb, k_ws);
  gemm_bt<2><<<512, 256, 0, stream>>>(xb, wvb, vt_ws);

  rope_kernel<<<2048, 256, 0, stream>>>(q_ws, k_ws, cb, sb);

  attn_kernel<<<512, 256, 0, stream>>>(q_ws, k_ws, vt_ws, attn_ws);

  gemm_bt<3><<<512, 256, 0, stream>>>(attn_ws, wob, d_out);
}

// Round 4
// 297.053 us; speedup vs baseline: 1.2660x; 1.1778x over previous
//
#include <hip/hip_runtime.h>

typedef __attribute__((ext_vector_type(8))) short short8;
typedef __attribute__((ext_vector_type(4))) float f32x4;
typedef __attribute__((ext_vector_type(16))) float f32x16;
typedef unsigned int u32;
typedef __attribute__((ext_vector_type(4))) u32 u32x4;
typedef unsigned short u16;

#define DEV __device__ __forceinline__

DEV void async16(const void* g, void* l) {
  __builtin_amdgcn_global_load_lds((const __attribute__((address_space(1))) u32*)g,
                                   (__attribute__((address_space(3))) u32*)l, 16, 0, 0);
}

DEV u16 f2bf(float f) {
  u32 u = __builtin_bit_cast(u32, f);
  u32 r = (u + 0x7FFFu + ((u >> 16) & 1u)) >> 16;
  return (u16)r;
}
DEV float bf2f(u16 h) { return __builtin_bit_cast(float, (u32)h << 16); }

// ---------------- cast f32 -> bf16 ----------------
__global__ void cast_bf16_kernel(const float* __restrict__ in, u16* __restrict__ out, int n4) {
  int stride = gridDim.x * blockDim.x;
  for (int i = blockIdx.x * blockDim.x + threadIdx.x; i < n4; i += stride) {
    float4 v = reinterpret_cast<const float4*>(in)[i];
    ushort4 o = make_ushort4(f2bf(v.x), f2bf(v.y), f2bf(v.z), f2bf(v.w));
    reinterpret_cast<ushort4*>(out)[i] = o;
  }
}

// ---------------- GEMM: C[M=4096][N=2048] = A[M][K=2048] * B[N][K]^T (bf16, f32 acc)
// MODE 0: write bf16 to [B,H,S,HD] ; MODE 2: write bf16 to [B,H,HD,S] ; MODE 3: write f32 row-major
template <int MODE>
__global__ __launch_bounds__(256) void gemm_bt(const u16* __restrict__ A,
                                               const u16* __restrict__ Bw,
                                               void* __restrict__ C) {
  constexpr int K = 2048;
  __shared__ char sm[32768];  // A tile [128][64] @0, B tile [128][64] @16384, swizzled
  const int tid = threadIdx.x;
  const int lane = tid & 63;
  const int w = tid >> 6;
  const int bx = blockIdx.x & 15;   // N/128 = 16
  const int by = blockIdx.x >> 4;   // M/128 = 32
  const int row0 = by * 128, col0 = bx * 128;
  const int wr = (w >> 1) * 64, wc = (w & 1) * 64;
  f32x4 acc[4][4] = {};

  for (int k0 = 0; k0 < K; k0 += 64) {
    __syncthreads();
#pragma unroll
    for (int i = 0; i < 4; ++i) {
      int slot = tid + i * 256;
      int r = slot >> 3, s = slot & 7;
      int sl = s ^ (r & 7);
      async16(A + (size_t)(row0 + r) * K + (k0 + sl * 8), sm + slot * 16);
    }
#pragma unroll
    for (int i = 0; i < 4; ++i) {
      int slot = tid + i * 256;
      int r = slot >> 3, s = slot & 7;
      int sl = s ^ (r & 7);
      async16(Bw + (size_t)(col0 + r) * K + (k0 + sl * 8), sm + 16384 + slot * 16);
    }
    __syncthreads();
#pragma unroll
    for (int kk = 0; kk < 2; ++kk) {
      short8 af[4], bfr[4];
#pragma unroll
      for (int mi = 0; mi < 4; ++mi) {
        int r = wr + mi * 16 + (lane & 15);
        int ps = (kk * 4 + (lane >> 4)) ^ (r & 7);
        af[mi] = *reinterpret_cast<const short8*>(sm + r * 128 + ps * 16);
      }
#pragma unroll
      for (int ni = 0; ni < 4; ++ni) {
        int r = wc + ni * 16 + (lane & 15);
        int ps = (kk * 4 + (lane >> 4)) ^ (r & 7);
        bfr[ni] = *reinterpret_cast<const short8*>(sm + 16384 + r * 128 + ps * 16);
      }
#pragma unroll
      for (int mi = 0; mi < 4; ++mi)
#pragma unroll
        for (int ni = 0; ni < 4; ++ni)
          acc[mi][ni] = __builtin_amdgcn_mfma_f32_16x16x32_bf16(af[mi], bfr[ni], acc[mi][ni], 0, 0, 0);
    }
  }
  // epilogue
#pragma unroll
  for (int mi = 0; mi < 4; ++mi)
#pragma unroll
    for (int ni = 0; ni < 4; ++ni)
#pragma unroll
      for (int r = 0; r < 4; ++r) {
        int gm = row0 + wr + mi * 16 + ((lane >> 4) << 2) + r;
        int gn = col0 + wc + ni * 16 + (lane & 15);
        float v = acc[mi][ni][r];
        if constexpr (MODE == 0) {
          int b = gm >> 11, s = gm & 2047, h = gn >> 7, hd = gn & 127;
          ((u16*)C)[(size_t)((b << 4) | h) * 262144 + (s << 7) + hd] = f2bf(v);
        } else if constexpr (MODE == 2) {
          int b = gm >> 11, s = gm & 2047, h = gn >> 7, hd = gn & 127;
          ((u16*)C)[(size_t)((b << 4) | h) * 262144 + (hd << 11) + s] = f2bf(v);
        } else {
          ((float*)C)[((size_t)gm << 11) + gn] = v;
        }
      }
}

// ---------------- RoPE in-place on q_ws/k_ws [B,H,S,HD]
// q additionally scaled by log2(e)/sqrt(HD) so attn can use exp2
__global__ void rope_kernel(u16* __restrict__ q, u16* __restrict__ k,
                            const float* __restrict__ cb, const float* __restrict__ sb) {
  const float rs = 0.127517436f;  // log2(e)/sqrt(128)
  const int NP = 2 * 16 * 2048 * 64;  // pairs per tensor
  int stride = gridDim.x * blockDim.x;
  for (int i = blockIdx.x * blockDim.x + threadIdx.x; i < 2 * NP; i += stride) {
    int p = (i < NP) ? i : i - NP;
    u16* base = (i < NP) ? q : k;
    float sc = (i < NP) ? rs : 1.0f;
    int fi = p & 63;
    int s = (p >> 6) & 2047;
    u32 v = *reinterpret_cast<u32*>(base + 2 * (size_t)p);
    float xr = bf2f((u16)(v & 0xFFFFu)), xi = bf2f((u16)(v >> 16));
    float c = cb[(s << 6) + fi], sn = sb[(s << 6) + fi];
    float orr = (xr * c - xi * sn) * sc;
    float oi = (xr * sn + xi * c) * sc;
    *reinterpret_cast<u32*>(base + 2 * (size_t)p) = (u32)f2bf(orr) | ((u32)f2bf(oi) << 16);
  }
}

// ---------------- causal flash attention (32x32 MFMA, swapped QK^T) ----
// 256 blocks = 32 bh x 8 pairs (XCD-clustered decode). 8 waves x 32 q-rows.
// Waves 0-3: q-tile pairA (128 rows); waves 4-7: q-tile 15-pairA. KVBLK=64 dbuf.
// Swapped QK^T (S^T, q=lane&31) -> in-register softmax (shfl_xor 32 combine);
// P packed to bf16 B-frags in-register (f2bf + shfl_xor half-exchange).
// PV computes O^T (rescale & 1/l per-lane); epilogue transposes via LDS.
__global__ __launch_bounds__(512, 2) void attn_kernel(const u16* __restrict__ q_ws,
                                                      const u16* __restrict__ k_ws,
                                                      const u16* __restrict__ vt_ws,
                                                      u16* __restrict__ attn_ws) {
  constexpr int S = 2048;
  constexpr float NEGBIG = -3.0e38f;  // finite mask value: exp2 -> 0, no inf arithmetic
  // dbuf b @ b*32768: K[64 rows][16 slots sw] 16KB + Vt[128 rows][8 slots sw] 16KB
  __shared__ char sm[65536];
  const int tid = threadIdx.x, lane = tid & 63, w = tid >> 6;
  const int hi = lane >> 5, l31 = lane & 31;
  const int bid = blockIdx.x;
  const int pairA = bid >> 5;                         // 0..7
  const int bh = ((bid & 7) << 2) | ((bid >> 3) & 3); // same bh -> same XCD
  const int qt = (w < 4) ? pairA : 15 - pairA;
  const int qr0 = qt * 128 + (w & 3) * 32;
  const int ntile = 32 - 2 * pairA;   // staged kv tiles (union of both q-tiles)
  const int my_nt = (qr0 >> 6) + 1;   // wave-active kv tiles

  const u16* qp = q_ws + (size_t)bh * S * 128;
  const u16* kp = k_ws + (size_t)bh * S * 128;
  const u16* vp = vt_ws + (size_t)bh * 128 * S;

  // Q fragments (B-operand): col=lane&31=q, k=8*hi+e per 16-k step
  short8 qf[8];
  {
    const u16* qr = qp + (size_t)(qr0 + l31) * 128 + hi * 8;
#pragma unroll
    for (int ks = 0; ks < 8; ++ks) qf[ks] = *reinterpret_cast<const short8*>(qr + ks * 16);
  }
  f32x16 accO[4];
#pragma unroll
  for (int dc = 0; dc < 4; ++dc)
#pragma unroll
    for (int r = 0; r < 16; ++r) accO[dc][r] = 0.f;
  float m = -1e30f, l = 0.f;

  auto stage = [&](int bufoff, int kv0) {
#pragma unroll
    for (int i = 0; i < 2; ++i) {  // K: 64 rows x 16 slots, 4-bit XOR swizzle
      int slot = tid + i * 512;
      int r = slot >> 4, s = slot & 15;
      async16(kp + (size_t)(kv0 + r) * 128 + ((s ^ (r & 15)) * 8), sm + bufoff + slot * 16);
    }
#pragma unroll
    for (int i = 0; i < 2; ++i) {  // Vt: 128 rows x 8 slots, 3-bit XOR swizzle
      int slot = tid + i * 512;
      int r = slot >> 3, s = slot & 7;
      async16(vp + (size_t)r * S + kv0 + ((s ^ (r & 7)) * 8), sm + bufoff + 16384 + slot * 16);
    }
  };

  stage(0, 0);
  __syncthreads();

  for (int t = 0; t < ntile; ++t) {
    const char* kb = sm + (t & 1) * 32768;
    const char* vb = kb + 16384;
    if (t + 1 < ntile) stage(((t + 1) & 1) * 32768, (t + 1) * 64);

    if (t < my_nt) {
      // ---- QK^T swapped: sacc[jc][r] = S^T[j = 32jc+cr(r,hi)][q = qr0+l31] ----
      f32x16 sacc[2];
#pragma unroll
      for (int jc = 0; jc < 2; ++jc)
#pragma unroll
        for (int r = 0; r < 16; ++r) sacc[jc][r] = 0.f;
      __builtin_amdgcn_s_setprio(1);
#pragma unroll
      for (int jc = 0; jc < 2; ++jc) {
        const char* krp = kb + (jc * 32 + l31) * 256;
        const int sw = l31 & 15;
#pragma unroll
        for (int ks = 0; ks < 8; ++ks) {
          short8 kf = *reinterpret_cast<const short8*>(krp + (((2 * ks + hi) ^ sw) << 4));
          sacc[jc] = __builtin_amdgcn_mfma_f32_32x32x16_bf16(kf, qf[ks], sacc[jc], 0, 0, 0);
        }
      }
      __builtin_amdgcn_s_setprio(0);
      // ---- causal mask (only the diagonal tile) ----
      if (t == my_nt - 1) {
#pragma unroll
        for (int jc = 0; jc < 2; ++jc) {
          int thr = qr0 + l31 - t * 64 - 32 * jc - 4 * hi;
#pragma unroll
          for (int r = 0; r < 16; ++r) {
            int c0 = (r & 3) + 8 * (r >> 2);
            if (c0 > thr) sacc[jc][r] = NEGBIG;
          }
        }
      }
      // ---- in-register online softmax (q = lane&31; partner half via shfl_xor 32) ----
      float pmA = NEGBIG, pmB = NEGBIG, pmC = NEGBIG, pmD = NEGBIG;
#pragma unroll
      for (int jc = 0; jc < 2; ++jc)
#pragma unroll
        for (int r = 0; r < 16; r += 4) {
          pmA = fmaxf(pmA, sacc[jc][r]);
          pmB = fmaxf(pmB, sacc[jc][r + 1]);
          pmC = fmaxf(pmC, sacc[jc][r + 2]);
          pmD = fmaxf(pmD, sacc[jc][r + 3]);
        }
      float pmax = fmaxf(fmaxf(pmA, pmB), fmaxf(pmC, pmD));
      pmax = fmaxf(pmax, __shfl_xor(pmax, 32, 64));
      float mnew = fmaxf(m, pmax);
      float scl = exp2f(m - mnew);
      m = mnew;
      float sA = 0.f, sB = 0.f, sC = 0.f, sD = 0.f;
#pragma unroll
      for (int jc = 0; jc < 2; ++jc)
#pragma unroll
        for (int r = 0; r < 16; r += 4) {
          float p0 = exp2f(sacc[jc][r] - mnew);
          float p1 = exp2f(sacc[jc][r + 1] - mnew);
          float p2 = exp2f(sacc[jc][r + 2] - mnew);
          float p3 = exp2f(sacc[jc][r + 3] - mnew);
          sacc[jc][r] = p0; sacc[jc][r + 1] = p1; sacc[jc][r + 2] = p2; sacc[jc][r + 3] = p3;
          sA += p0; sB += p1; sC += p2; sD += p3;
        }
      float ps = (sA + sB) + (sC + sD);
      ps += __shfl_xor(ps, 32, 64);
      l = l * scl + ps;
#pragma unroll
      for (int dc = 0; dc < 4; ++dc)
#pragma unroll
        for (int r = 0; r < 16; ++r) accO[dc][r] *= scl;
      // ---- pack P -> bf16 B-fragments (f2bf + shfl_xor half-exchange) ----
      // lane needs j = 16ks + 8hi + {0..7}; own words cover {J+4hi..} pattern
      short8 pfrag[4];
#pragma unroll
      for (int ks = 0; ks < 4; ++ks) {
        const int jc = ks >> 1, u8 = (ks & 1) * 8;
        u32 wA = (u32)f2bf(sacc[jc][u8 + 0]) | ((u32)f2bf(sacc[jc][u8 + 1]) << 16);
        u32 wB = (u32)f2bf(sacc[jc][u8 + 2]) | ((u32)f2bf(sacc[jc][u8 + 3]) << 16);
        u32 wC = (u32)f2bf(sacc[jc][u8 + 4]) | ((u32)f2bf(sacc[jc][u8 + 5]) << 16);
        u32 wD = (u32)f2bf(sacc[jc][u8 + 6]) | ((u32)f2bf(sacc[jc][u8 + 7]) << 16);
        u32 qA = __shfl_xor(wA, 32, 64);
        u32 qB = __shfl_xor(wB, 32, 64);
        u32 qC = __shfl_xor(wC, 32, 64);
        u32 qD = __shfl_xor(wD, 32, 64);
        u32x4 t4;
        t4.x = hi ? qC : wA;
        t4.y = hi ? qD : wB;
        t4.z = hi ? wC : qA;
        t4.w = hi ? wD : qB;
        pfrag[ks] = __builtin_bit_cast(short8, t4);
      }
      // ---- PV: accO[dc][r] = O^T[d = 32dc+cr(r,hi)][q = qr0+l31] ----
      __builtin_amdgcn_s_setprio(1);
#pragma unroll
      for (int ks = 0; ks < 4; ++ks) {
#pragma unroll
        for (int dc = 0; dc < 4; ++dc) {
          const char* vrp = vb + (dc * 32 + l31) * 128;
          short8 vf = *reinterpret_cast<const short8*>(vrp + (((2 * ks + hi) ^ (l31 & 7)) << 4));
          accO[dc] = __builtin_amdgcn_mfma_f32_32x32x16_bf16(vf, pfrag[ks], accO[dc], 0, 0, 0);
        }
      }
      __builtin_amdgcn_s_setprio(0);
    }
    __syncthreads();  // drains vmcnt (prefetch landed) + protects dbuf reuse
  }

  // ---- epilogue: O^T -> LDS (swizzled) -> coalesced bf16 rows of attn_ws [B,S,D] ----
  const int b = bh >> 4, h = bh & 15;
  char* tb = sm + w * 8192;  // per-wave [32 q][128 d] bf16 tile
  float inv = (l > 0.f) ? 1.0f / l : 0.f;
#pragma unroll
  for (int dc = 0; dc < 4; ++dc)
#pragma unroll
    for (int r = 0; r < 16; ++r) {
      int d = dc * 32 + (r & 3) + 8 * (r >> 2) + 4 * hi;
      int byte = l31 * 256 + d * 2;
      *reinterpret_cast<u16*>(tb + (byte ^ ((l31 & 7) << 4))) = f2bf(accO[dc][r] * inv);
    }
  asm volatile("s_waitcnt lgkmcnt(0)" ::: "memory");
#pragma unroll
  for (int i = 0; i < 8; ++i) {
    int r = i * 4 + (lane >> 4);
    int s = lane & 15;
    f32x4 v = *reinterpret_cast<const f32x4*>(tb + r * 256 + ((s ^ (r & 7)) << 4));
    size_t addr = ((size_t)(b * 2048 + qr0 + r) << 11) + (h << 7) + s * 8;
    *reinterpret_cast<f32x4*>(attn_ws + addr) = v;
  }
}

extern "C" void kernel_launch(void* const* d_in, const int* in_sizes, int n_in,
                              void* d_out, int out_size, void* d_ws, size_t ws_size,
                              hipStream_t stream) {
  const float* x = (const float*)d_in[0];
  // d_in[1] = start_pos (0), d_in[4] = mask (causal) — handled analytically
  const float* cb = (const float*)d_in[2];
  const float* sb = (const float*)d_in[3];
  const float* wq = (const float*)d_in[5];
  const float* wk = (const float*)d_in[6];
  const float* wv = (const float*)d_in[7];
  const float* wo = (const float*)d_in[8];

  char* p = (char*)d_ws;
  u16* xb  = (u16*)p; p += (size_t)4096 * 2048 * 2;
  u16* wqb = (u16*)p; p += (size_t)2048 * 2048 * 2;
  u16* wkb = (u16*)p; p += (size_t)2048 * 2048 * 2;
  u16* wvb = (u16*)p; p += (size_t)2048 * 2048 * 2;
  u16* wob = (u16*)p; p += (size_t)2048 * 2048 * 2;
  u16* q_ws = (u16*)p; p += (size_t)4096 * 2048 * 2;
  u16* k_ws = (u16*)p; p += (size_t)4096 * 2048 * 2;
  u16* vt_ws = (u16*)p; p += (size_t)4096 * 2048 * 2;
  u16* attn_ws = xb;  // xb is dead after the V projection; reuse it

  cast_bf16_kernel<<<2048, 256, 0, stream>>>(x, xb, 4096 * 2048 / 4);
  cast_bf16_kernel<<<1024, 256, 0, stream>>>(wq, wqb, 2048 * 2048 / 4);
  cast_bf16_kernel<<<1024, 256, 0, stream>>>(wk, wkb, 2048 * 2048 / 4);
  cast_bf16_kernel<<<1024, 256, 0, stream>>>(wv, wvb, 2048 * 2048 / 4);
  cast_bf16_kernel<<<1024, 256, 0, stream>>>(wo, wob, 2048 * 2048 / 4);

  gemm_bt<0><<<512, 256, 0, stream>>>(xb, wqb, q_ws);
  gemm_bt<0><<<512, 256, 0, stream>>>(xb, wkb, k_ws);
  gemm_bt<2><<<512, 256, 0, stream>>>(xb, wvb, vt_ws);

  rope_kernel<<<2048, 256, 0, stream>>>(q_ws, k_ws, cb, sb);

  attn_kernel<<<256, 512, 0, stream>>>(q_ws, k_ws, vt_ws, attn_ws);

  gemm_bt<3><<<512, 256, 0, stream>>>(attn_ws, wob, d_out);
}

// Round 5
// 271.835 us; speedup vs baseline: 1.3834x; 1.0928x over previous
//
#include <hip/hip_runtime.h>

typedef __attribute__((ext_vector_type(8))) short short8;
typedef __attribute__((ext_vector_type(4))) float f32x4;
typedef __attribute__((ext_vector_type(16))) float f32x16;
typedef unsigned int u32;
typedef __attribute__((ext_vector_type(4))) u32 u32x4;
typedef unsigned short u16;

#define DEV __device__ __forceinline__

DEV void async16(const void* g, void* l) {
  __builtin_amdgcn_global_load_lds((const __attribute__((address_space(1))) u32*)g,
                                   (__attribute__((address_space(3))) u32*)l, 16, 0, 0);
}

DEV u16 f2bf(float f) {
  u32 u = __builtin_bit_cast(u32, f);
  u32 r = (u + 0x7FFFu + ((u >> 16) & 1u)) >> 16;
  return (u16)r;
}
DEV float bf2f(u16 h) { return __builtin_bit_cast(float, (u32)h << 16); }

DEV u32 cvtpk(float lo, float hi) {  // packs {bf16(lo), bf16(hi)} -> u32 (lo in low16)
  u32 r;
  asm("v_cvt_pk_bf16_f32 %0, %1, %2" : "=v"(r) : "v"(lo), "v"(hi));
  return r;
}

// ---------------- fused cast f32 -> bf16 of x + 4 weights (dst regions contiguous) --
__global__ void cast_all_kernel(const float* __restrict__ x, const float* __restrict__ wq,
                                const float* __restrict__ wk, const float* __restrict__ wv,
                                const float* __restrict__ wo, u16* __restrict__ out) {
  constexpr int XN = 2097152;  // x float4 count (4096*2048/4)
  constexpr int WN = 1048576;  // each weight float4 count
  constexpr int TOT = XN + 4 * WN;
  int stride = gridDim.x * blockDim.x;
  for (int i = blockIdx.x * blockDim.x + threadIdx.x; i < TOT; i += stride) {
    const float* src;
    int off;
    if (i < XN) {
      src = x; off = i;
    } else {
      int j = i - XN, wsel = j >> 20;
      const float* ws4[4] = {wq, wk, wv, wo};
      src = ws4[wsel]; off = j & (WN - 1);
    }
    float4 v = reinterpret_cast<const float4*>(src)[off];
    ushort4 o = make_ushort4(f2bf(v.x), f2bf(v.y), f2bf(v.z), f2bf(v.w));
    reinterpret_cast<ushort4*>(out)[i] = o;
  }
}

// ---------------- GEMM: C[M=4096][N] = A[M][K=2048] * B[N][K]^T (bf16, f32 acc)
// MODE 4: N=6144 fused QKV -> route to q_ws/k_ws ([B,H,S,HD]) / vt_ws ([B,H,HD,S])
// MODE 3: N=2048, write f32 row-major to C0
template <int MODE>
__global__ __launch_bounds__(256) void gemm_bt(const u16* __restrict__ A,
                                               const u16* __restrict__ Bw,
                                               void* __restrict__ C0,
                                               u16* __restrict__ C1,
                                               u16* __restrict__ C2) {
  constexpr int K = 2048;
  __shared__ char sm[32768];  // A tile [128][64] @0, B tile [128][64] @16384, swizzled
  const int tid = threadIdx.x;
  const int lane = tid & 63;
  const int w = tid >> 6;
  const int by = blockIdx.x & 31;   // M/128 = 32
  const int bx = blockIdx.x >> 5;   // N/128 blocks
  const int row0 = by * 128, col0 = bx * 128;
  const int wr = (w >> 1) * 64, wc = (w & 1) * 64;
  f32x4 acc[4][4] = {};

  for (int k0 = 0; k0 < K; k0 += 64) {
    __syncthreads();
#pragma unroll
    for (int i = 0; i < 4; ++i) {
      int slot = tid + i * 256;
      int r = slot >> 3, s = slot & 7;
      int sl = s ^ (r & 7);
      async16(A + (size_t)(row0 + r) * K + (k0 + sl * 8), sm + slot * 16);
    }
#pragma unroll
    for (int i = 0; i < 4; ++i) {
      int slot = tid + i * 256;
      int r = slot >> 3, s = slot & 7;
      int sl = s ^ (r & 7);
      async16(Bw + (size_t)(col0 + r) * K + (k0 + sl * 8), sm + 16384 + slot * 16);
    }
    __syncthreads();
#pragma unroll
    for (int kk = 0; kk < 2; ++kk) {
      short8 af[4], bfr[4];
#pragma unroll
      for (int mi = 0; mi < 4; ++mi) {
        int r = wr + mi * 16 + (lane & 15);
        int ps = (kk * 4 + (lane >> 4)) ^ (r & 7);
        af[mi] = *reinterpret_cast<const short8*>(sm + r * 128 + ps * 16);
      }
#pragma unroll
      for (int ni = 0; ni < 4; ++ni) {
        int r = wc + ni * 16 + (lane & 15);
        int ps = (kk * 4 + (lane >> 4)) ^ (r & 7);
        bfr[ni] = *reinterpret_cast<const short8*>(sm + 16384 + r * 128 + ps * 16);
      }
#pragma unroll
      for (int mi = 0; mi < 4; ++mi)
#pragma unroll
        for (int ni = 0; ni < 4; ++ni)
          acc[mi][ni] = __builtin_amdgcn_mfma_f32_16x16x32_bf16(af[mi], bfr[ni], acc[mi][ni], 0, 0, 0);
    }
  }
  // epilogue
#pragma unroll
  for (int mi = 0; mi < 4; ++mi)
#pragma unroll
    for (int ni = 0; ni < 4; ++ni)
#pragma unroll
      for (int r = 0; r < 4; ++r) {
        int gm = row0 + wr + mi * 16 + ((lane >> 4) << 2) + r;
        int gn = col0 + wc + ni * 16 + (lane & 15);
        float v = acc[mi][ni][r];
        if constexpr (MODE == 4) {
          int tsel = gn >> 11, nn = gn & 2047;
          int b = gm >> 11, s = gm & 2047, h = nn >> 7, hd = nn & 127;
          u16* dst = (tsel == 0) ? (u16*)C0 : (tsel == 1) ? C1 : C2;
          if (tsel < 2)
            dst[(size_t)((b << 4) | h) * 262144 + (s << 7) + hd] = f2bf(v);
          else
            dst[(size_t)((b << 4) | h) * 262144 + (hd << 11) + s] = f2bf(v);
        } else {
          ((float*)C0)[((size_t)gm << 11) + gn] = v;
        }
      }
}

// ---------------- RoPE in-place on q_ws/k_ws [B,H,S,HD]
// q additionally scaled by log2(e)/sqrt(HD) so attn can use exp2
__global__ void rope_kernel(u16* __restrict__ q, u16* __restrict__ k,
                            const float* __restrict__ cb, const float* __restrict__ sb) {
  const float rs = 0.127517436f;  // log2(e)/sqrt(128)
  const int NP = 2 * 16 * 2048 * 64;  // pairs per tensor
  int stride = gridDim.x * blockDim.x;
  for (int i = blockIdx.x * blockDim.x + threadIdx.x; i < 2 * NP; i += stride) {
    int p = (i < NP) ? i : i - NP;
    u16* base = (i < NP) ? q : k;
    float sc = (i < NP) ? rs : 1.0f;
    int fi = p & 63;
    int s = (p >> 6) & 2047;
    u32 v = *reinterpret_cast<u32*>(base + 2 * (size_t)p);
    float xr = bf2f((u16)(v & 0xFFFFu)), xi = bf2f((u16)(v >> 16));
    float c = cb[(s << 6) + fi], sn = sb[(s << 6) + fi];
    float orr = (xr * c - xi * sn) * sc;
    float oi = (xr * sn + xi * c) * sc;
    *reinterpret_cast<u32*>(base + 2 * (size_t)p) = (u32)f2bf(orr) | ((u32)f2bf(oi) << 16);
  }
}

// ---------------- causal flash attention (32x32 MFMA, swapped QK^T) ----
// 512 blocks = 32 bh (XCD-clustered) x 16 q-tiles of 128 rows; 4 waves x 32 q-rows.
// qt decode pairs blocks (bid, bid+256) -> qt + qt' = 15 (balanced per-CU staged work).
// KVBLK=64 double-buffered (64KB LDS -> 2 blocks/CU). Swapped QK^T -> in-register
// softmax (shfl_xor 32 combine) + defer-max (T13); P packed via v_cvt_pk_bf16_f32 +
// shfl_xor half-exchange. PV computes O^T; epilogue transposes via LDS.
__global__ __launch_bounds__(256, 2) void attn_kernel(const u16* __restrict__ q_ws,
                                                      const u16* __restrict__ k_ws,
                                                      const u16* __restrict__ vt_ws,
                                                      u16* __restrict__ attn_ws) {
  constexpr int S = 2048;
  constexpr float NEGBIG = -3.0e38f;  // finite mask value: exp2 -> 0, no inf arithmetic
  // dbuf b @ b*32768: K[64 rows][16 slots sw] 16KB + Vt[128 rows][8 slots sw] 16KB
  __shared__ char sm[65536];
  const int tid = threadIdx.x, lane = tid & 63, w = tid >> 6;
  const int hi = lane >> 5, l31 = lane & 31;
  const int bid = blockIdx.x;
  const int qtr = bid >> 5;                           // 0..15
  const int qt = (qtr < 8) ? qtr : 23 - qtr;          // pair (bid,bid+256): qt+qt'=15
  const int bh = ((bid & 7) << 2) | ((bid >> 3) & 3); // same bh -> same XCD
  const int qr0 = qt * 128 + w * 32;
  const int ntile = 2 * qt + 2;       // staged kv tiles
  const int my_nt = (qr0 >> 6) + 1;   // wave-active kv tiles

  const u16* qp = q_ws + (size_t)bh * S * 128;
  const u16* kp = k_ws + (size_t)bh * S * 128;
  const u16* vp = vt_ws + (size_t)bh * 128 * S;

  // Q fragments (B-operand): col=lane&31=q, k=8*hi+e per 16-k step
  short8 qf[8];
  {
    const u16* qr = qp + (size_t)(qr0 + l31) * 128 + hi * 8;
#pragma unroll
    for (int ks = 0; ks < 8; ++ks) qf[ks] = *reinterpret_cast<const short8*>(qr + ks * 16);
  }
  f32x16 accO[4];
#pragma unroll
  for (int dc = 0; dc < 4; ++dc)
#pragma unroll
    for (int r = 0; r < 16; ++r) accO[dc][r] = 0.f;
  float m = -1e30f, l = 0.f;

  auto stage = [&](int bufoff, int kv0) {
#pragma unroll
    for (int i = 0; i < 4; ++i) {  // K: 64 rows x 16 slots, 4-bit XOR swizzle
      int slot = tid + i * 256;
      int r = slot >> 4, s = slot & 15;
      async16(kp + (size_t)(kv0 + r) * 128 + ((s ^ (r & 15)) * 8), sm + bufoff + slot * 16);
    }
#pragma unroll
    for (int i = 0; i < 4; ++i) {  // Vt: 128 rows x 8 slots, 3-bit XOR swizzle
      int slot = tid + i * 256;
      int r = slot >> 3, s = slot & 7;
      async16(vp + (size_t)r * S + kv0 + ((s ^ (r & 7)) * 8), sm + bufoff + 16384 + slot * 16);
    }
  };

  stage(0, 0);
  __syncthreads();

  for (int t = 0; t < ntile; ++t) {
    const char* kb = sm + (t & 1) * 32768;
    const char* vb = kb + 16384;
    if (t + 1 < ntile) stage(((t + 1) & 1) * 32768, (t + 1) * 64);

    if (t < my_nt) {
      // ---- QK^T swapped: sacc[jc][r] = S^T[j = 32jc+cr(r,hi)][q = qr0+l31] ----
      f32x16 sacc[2];
#pragma unroll
      for (int jc = 0; jc < 2; ++jc)
#pragma unroll
        for (int r = 0; r < 16; ++r) sacc[jc][r] = 0.f;
      __builtin_amdgcn_s_setprio(1);
#pragma unroll
      for (int jc = 0; jc < 2; ++jc) {
        const char* krp = kb + (jc * 32 + l31) * 256;
        const int sw = l31 & 15;
#pragma unroll
        for (int ks = 0; ks < 8; ++ks) {
          short8 kf = *reinterpret_cast<const short8*>(krp + (((2 * ks + hi) ^ sw) << 4));
          sacc[jc] = __builtin_amdgcn_mfma_f32_32x32x16_bf16(kf, qf[ks], sacc[jc], 0, 0, 0);
        }
      }
      __builtin_amdgcn_s_setprio(0);
      // ---- causal mask (only the diagonal tile) ----
      if (t == my_nt - 1) {
#pragma unroll
        for (int jc = 0; jc < 2; ++jc) {
          int thr = qr0 + l31 - t * 64 - 32 * jc - 4 * hi;
#pragma unroll
          for (int r = 0; r < 16; ++r) {
            int c0 = (r & 3) + 8 * (r >> 2);
            if (c0 > thr) sacc[jc][r] = NEGBIG;
          }
        }
      }
      // ---- in-register online softmax; defer-max (T13) ----
      float pmA = NEGBIG, pmB = NEGBIG, pmC = NEGBIG, pmD = NEGBIG;
#pragma unroll
      for (int jc = 0; jc < 2; ++jc)
#pragma unroll
        for (int r = 0; r < 16; r += 4) {
          pmA = fmaxf(pmA, sacc[jc][r]);
          pmB = fmaxf(pmB, sacc[jc][r + 1]);
          pmC = fmaxf(pmC, sacc[jc][r + 2]);
          pmD = fmaxf(pmD, sacc[jc][r + 3]);
        }
      float pmax = fmaxf(fmaxf(pmA, pmB), fmaxf(pmC, pmD));
      pmax = fmaxf(pmax, __shfl_xor(pmax, 32, 64));
      if (!__all(pmax - m <= 8.0f)) {  // rescale path (wave-uniform)
        float mnew = fmaxf(m, pmax);
        float scl = exp2f(m - mnew);
        m = mnew;
        l *= scl;
#pragma unroll
        for (int dc = 0; dc < 4; ++dc)
#pragma unroll
          for (int r = 0; r < 16; ++r) accO[dc][r] *= scl;
      }
      float sA = 0.f, sB = 0.f, sC = 0.f, sD = 0.f;
#pragma unroll
      for (int jc = 0; jc < 2; ++jc)
#pragma unroll
        for (int r = 0; r < 16; r += 4) {
          float p0 = exp2f(sacc[jc][r] - m);
          float p1 = exp2f(sacc[jc][r + 1] - m);
          float p2 = exp2f(sacc[jc][r + 2] - m);
          float p3 = exp2f(sacc[jc][r + 3] - m);
          sacc[jc][r] = p0; sacc[jc][r + 1] = p1; sacc[jc][r + 2] = p2; sacc[jc][r + 3] = p3;
          sA += p0; sB += p1; sC += p2; sD += p3;
        }
      float ps = (sA + sB) + (sC + sD);
      ps += __shfl_xor(ps, 32, 64);
      l += ps;
      // ---- pack P -> bf16 B-fragments (cvt_pk + shfl_xor half-exchange) ----
      short8 pfrag[4];
#pragma unroll
      for (int ks = 0; ks < 4; ++ks) {
        const int jc = ks >> 1, u8 = (ks & 1) * 8;
        u32 wA = cvtpk(sacc[jc][u8 + 0], sacc[jc][u8 + 1]);
        u32 wB = cvtpk(sacc[jc][u8 + 2], sacc[jc][u8 + 3]);
        u32 wC = cvtpk(sacc[jc][u8 + 4], sacc[jc][u8 + 5]);
        u32 wD = cvtpk(sacc[jc][u8 + 6], sacc[jc][u8 + 7]);
        u32 qA = __shfl_xor(wA, 32, 64);
        u32 qB = __shfl_xor(wB, 32, 64);
        u32 qC = __shfl_xor(wC, 32, 64);
        u32 qD = __shfl_xor(wD, 32, 64);
        u32x4 t4;
        t4.x = hi ? qC : wA;
        t4.y = hi ? qD : wB;
        t4.z = hi ? wC : qA;
        t4.w = hi ? wD : qB;
        pfrag[ks] = __builtin_bit_cast(short8, t4);
      }
      // ---- PV: accO[dc][r] = O^T[d = 32dc+cr(r,hi)][q = qr0+l31] ----
      __builtin_amdgcn_s_setprio(1);
#pragma unroll
      for (int ks = 0; ks < 4; ++ks) {
#pragma unroll
        for (int dc = 0; dc < 4; ++dc) {
          const char* vrp = vb + (dc * 32 + l31) * 128;
          short8 vf = *reinterpret_cast<const short8*>(vrp + (((2 * ks + hi) ^ (l31 & 7)) << 4));
          accO[dc] = __builtin_amdgcn_mfma_f32_32x32x16_bf16(vf, pfrag[ks], accO[dc], 0, 0, 0);
        }
      }
      __builtin_amdgcn_s_setprio(0);
    }
    __syncthreads();  // drains vmcnt (prefetch landed) + protects dbuf reuse
  }

  // ---- epilogue: O^T -> LDS (swizzled) -> coalesced bf16 rows of attn_ws [B,S,D] ----
  const int b = bh >> 4, h = bh & 15;
  char* tb = sm + w * 8192;  // per-wave [32 q][128 d] bf16 tile
  float inv = (l > 0.f) ? 1.0f / l : 0.f;
#pragma unroll
  for (int dc = 0; dc < 4; ++dc)
#pragma unroll
    for (int r = 0; r < 16; ++r) {
      int d = dc * 32 + (r & 3) + 8 * (r >> 2) + 4 * hi;
      int byte = l31 * 256 + d * 2;
      *reinterpret_cast<u16*>(tb + (byte ^ ((l31 & 7) << 4))) = f2bf(accO[dc][r] * inv);
    }
  asm volatile("s_waitcnt lgkmcnt(0)" ::: "memory");
#pragma unroll
  for (int i = 0; i < 8; ++i) {
    int r = i * 4 + (lane >> 4);
    int s = lane & 15;
    f32x4 v = *reinterpret_cast<const f32x4*>(tb + r * 256 + ((s ^ (r & 7)) << 4));
    size_t addr = ((size_t)(b * 2048 + qr0 + r) << 11) + (h << 7) + s * 8;
    *reinterpret_cast<f32x4*>(attn_ws + addr) = v;
  }
}

extern "C" void kernel_launch(void* const* d_in, const int* in_sizes, int n_in,
                              void* d_out, int out_size, void* d_ws, size_t ws_size,
                              hipStream_t stream) {
  const float* x = (const float*)d_in[0];
  // d_in[1] = start_pos (0), d_in[4] = mask (causal) — handled analytically
  const float* cb = (const float*)d_in[2];
  const float* sb = (const float*)d_in[3];
  const float* wq = (const float*)d_in[5];
  const float* wk = (const float*)d_in[6];
  const float* wv = (const float*)d_in[7];
  const float* wo = (const float*)d_in[8];

  char* p = (char*)d_ws;
  u16* xb  = (u16*)p; p += (size_t)4096 * 2048 * 2;
  u16* wqb = (u16*)p; p += (size_t)2048 * 2048 * 2;  // wq,wk,wv,wo contiguous ->
  u16* wkb = (u16*)p; p += (size_t)2048 * 2048 * 2;  // fused QKV B = wqb[0..6144)
  u16* wvb = (u16*)p; p += (size_t)2048 * 2048 * 2;
  u16* wob = (u16*)p; p += (size_t)2048 * 2048 * 2;
  u16* q_ws = (u16*)p; p += (size_t)4096 * 2048 * 2;
  u16* k_ws = (u16*)p; p += (size_t)4096 * 2048 * 2;
  u16* vt_ws = (u16*)p; p += (size_t)4096 * 2048 * 2;
  u16* attn_ws = xb;  // xb is dead after the QKV projection; reuse it
  (void)wkb; (void)wvb;

  cast_all_kernel<<<3072, 256, 0, stream>>>(x, wq, wk, wv, wo, xb);

  gemm_bt<4><<<1536, 256, 0, stream>>>(xb, wqb, q_ws, k_ws, vt_ws);

  rope_kernel<<<2048, 256, 0, stream>>>(q_ws, k_ws, cb, sb);

  attn_kernel<<<512, 256, 0, stream>>>(q_ws, k_ws, vt_ws, attn_ws);

  gemm_bt<3><<<512, 256, 0, stream>>>(attn_ws, wob, d_out, nullptr, nullptr);
}